// Round 11
// baseline (258.449 us; speedup 1.0000x reference)
//
#include <hip/hip_runtime.h>
#include <hip/hip_bf16.h>

// RelAttention (Transformer-XL style) on MI355X.
// fp32 in/out; internal bf16 MFMA w/ fp32 accum.
// B=4, S=1024, D=1024, H=16, DH=64, BH=64. SCALE = 1/32.
//
// Pipeline: cvt -> fused QKV GEMM (m97-style with TWO-PLANE BK=64:
// 8 gll16 + 32 MFMA per barrier-pair, halving the vmcnt(0) barrier
// drains; grid dim3(24,32) r8 placement — DO NOT swizzle, r9 lesson)
// -> fused rel-attention (r8: 64-row tiles, 8 waves, swapped-operand
// MFMA, packed u16x4 LDS, K/Pos prefetch) -> final GEMM (64x64, r8).
//
// Learned constraints: occupancy is NOT the attn lever (r1/r5/r6);
// __launch_bounds__ VGPR cap is 256/min_waves (r4); V-store coalescing
// NOT the qkv bottleneck (r8); qkv grid placement affects ATTN via
// XCD-L2 residency of its outputs (r9); fin 128x64@2/CU is neutral
// vs 64x64@4/CU (r10) -> keep r8's fin64.

typedef __bf16 bf16x8 __attribute__((ext_vector_type(8)));
typedef float  f32x4  __attribute__((ext_vector_type(4)));
typedef unsigned short u16x4 __attribute__((ext_vector_type(4)));

struct alignas(16) U128 { unsigned long long lo, hi; };

__device__ __forceinline__ bf16x8 ldg8(const __hip_bfloat16* p) {
    U128 u = *reinterpret_cast<const U128*>(p);
    return __builtin_bit_cast(bf16x8, u);
}

__device__ __forceinline__ __bf16 f2b(float f) {
    __hip_bfloat16 h = __float2bfloat16(f);
    return __builtin_bit_cast(__bf16, h);
}
__device__ __forceinline__ unsigned short f2bu(float f) {
    __hip_bfloat16 h = __float2bfloat16(f);
    return __builtin_bit_cast(unsigned short, h);
}
__device__ __forceinline__ float b2f(__bf16 b) {
    __hip_bfloat16 h = __builtin_bit_cast(__hip_bfloat16, b);
    return __bfloat162float(h);
}
__device__ __forceinline__ float bu2f(unsigned short u) {
    __hip_bfloat16 h = __builtin_bit_cast(__hip_bfloat16, u);
    return __bfloat162float(h);
}

__device__ __forceinline__ bf16x8 ldg8cvt(const float* p) {
    f32x4 a = *reinterpret_cast<const f32x4*>(p);
    f32x4 b = *reinterpret_cast<const f32x4*>(p + 4);
    bf16x8 r;
    r[0] = f2b(a[0]); r[1] = f2b(a[1]); r[2] = f2b(a[2]); r[3] = f2b(a[3]);
    r[4] = f2b(b[0]); r[5] = f2b(b[1]); r[6] = f2b(b[2]); r[7] = f2b(b[3]);
    return r;
}

#define MFMA16(a, b, c) __builtin_amdgcn_mfma_f32_16x16x32_bf16((a), (b), (c), 0, 0, 0)

// C1 = log2(e) * SCALE = log2(e)/32. Q is pre-scaled by this so the
// softmax exponent is exp2(bd' + ac') with NO fma and NO shift constant.
#define C1F 0.0450843334f

__device__ __forceinline__ void gll16(const __hip_bfloat16* g, void* lds_wave_base) {
    __builtin_amdgcn_global_load_lds(
        (const __attribute__((address_space(1))) void*)g,
        (__attribute__((address_space(3))) void*)lds_wave_base,
        16, 0, 0);
}

// ---------------------------------------------------------------------------
// fp32 -> bf16: x(4M), pos(4M), Wq/Wk/Wv(3M stacked), Wc(1M) = 12M elems.
// ---------------------------------------------------------------------------
__global__ __launch_bounds__(256) void cvt_kernel(
    const float* __restrict__ x,  const float* __restrict__ pos,
    const float* __restrict__ wq, const float* __restrict__ wk,
    const float* __restrict__ wv, const float* __restrict__ wc,
    __hip_bfloat16* __restrict__ xb, __hip_bfloat16* __restrict__ posb,
    __hip_bfloat16* __restrict__ wqkvb, __hip_bfloat16* __restrict__ wcb)
{
    const size_t base = ((size_t)blockIdx.x * 256 + threadIdx.x) * 8;
    const size_t M1 = (size_t)1 << 20;
    const float* src; __hip_bfloat16* dst; size_t o;
    if (base < 4*M1)        { src = x;   dst = xb;           o = base; }
    else if (base < 8*M1)   { src = pos; dst = posb;         o = base - 4*M1; }
    else if (base < 9*M1)   { src = wq;  dst = wqkvb;        o = base - 8*M1; }
    else if (base < 10*M1)  { src = wk;  dst = wqkvb + M1;   o = base - 9*M1; }
    else if (base < 11*M1)  { src = wv;  dst = wqkvb + 2*M1; o = base - 10*M1; }
    else                    { src = wc;  dst = wcb;          o = base - 11*M1; }
    *(bf16x8*)(dst + o) = ldg8cvt(src + o);
}

// ---------------------------------------------------------------------------
// QKV GEMM: C[m][n] = sum_k A[m][k]*Bm[n][k], Bm=[3072][1024].
// n<1024 -> Qu = (C+bq+u)*C1 (PRE-SCALED); <2048 -> Kb = C+bk;
// else Vt head-transposed = C+bv (LDS-staged coalesced write).
// TWO-PLANE BK=64: each 64-K step stages two [128][32] planes with the
// proven r8 pattern (identical global addr sequence, chunk layout, and
// fragment-read conflict profile) -> one barrier-pair per 32 MFMA
// instead of per 16. Grid dim3(24,32) — r8 placement (r9 lesson).
// ---------------------------------------------------------------------------
__global__ __launch_bounds__(256) void gemm_qkv(
    const __hip_bfloat16* __restrict__ A,
    const __hip_bfloat16* __restrict__ Bm,
    const float* __restrict__ bq, const float* __restrict__ bk,
    const float* __restrict__ bv, const float* __restrict__ u,
    __hip_bfloat16* __restrict__ Qu,
    __hip_bfloat16* __restrict__ Kb, __hip_bfloat16* __restrict__ Vt)
{
    // Union: staging (4 planes x 4096 elems = 16384) during K-loop;
    // V-transpose tile [128][132] = 16896 elems in the epilogue.
    __shared__ __attribute__((aligned(16))) __hip_bfloat16 Smem[128 * 132];
    __hip_bfloat16* As0 = Smem;
    __hip_bfloat16* As1 = Smem + 4096;
    __hip_bfloat16* Bs0 = Smem + 8192;
    __hip_bfloat16* Bs1 = Smem + 12288;

    const int tid  = threadIdx.x;
    const int lane = tid & 63, w = tid >> 6;
    const int quad = lane >> 4, c16 = lane & 15;
    const int wm = w >> 1, wn = w & 1;
    const int m0 = blockIdx.y * 128;
    const int n0 = blockIdx.x * 128;

    const int srow = w * 16 + (lane >> 2);
    const int scol = (lane & 3) * 8;
    const __hip_bfloat16* gA0 = A  + (size_t)(m0 + srow) * 1024 + scol;
    const __hip_bfloat16* gA1 = gA0 + (size_t)64 * 1024;
    const __hip_bfloat16* gB0 = Bm + (size_t)(n0 + srow) * 1024 + scol;
    const __hip_bfloat16* gB1 = gB0 + (size_t)64 * 1024;
    char* ldsA00 = (char*)As0 + (w << 10);
    char* ldsA01 = ldsA00 + 4096;
    char* ldsA10 = (char*)As1 + (w << 10);
    char* ldsA11 = ldsA10 + 4096;
    char* ldsB00 = (char*)Bs0 + (w << 10);
    char* ldsB01 = ldsB00 + 4096;
    char* ldsB10 = (char*)Bs1 + (w << 10);
    char* ldsB11 = ldsB10 + 4096;

    f32x4 acc[4][4] = {};

    for (int k0 = 0; k0 < 1024; k0 += 64) {
        gll16(gA0 + k0,      ldsA00);
        gll16(gA1 + k0,      ldsA01);
        gll16(gA0 + k0 + 32, ldsA10);
        gll16(gA1 + k0 + 32, ldsA11);
        gll16(gB0 + k0,      ldsB00);
        gll16(gB1 + k0,      ldsB01);
        gll16(gB0 + k0 + 32, ldsB10);
        gll16(gB1 + k0 + 32, ldsB11);
        __syncthreads();

        {
            bf16x8 af[4], bfr[4];
            #pragma unroll
            for (int i = 0; i < 4; ++i) {
                af[i]  = *(const bf16x8*)&As0[(wm * 64 + i * 16 + c16) * 32 + quad * 8];
                bfr[i] = *(const bf16x8*)&Bs0[(wn * 64 + i * 16 + c16) * 32 + quad * 8];
            }
            #pragma unroll
            for (int mi = 0; mi < 4; ++mi)
                #pragma unroll
                for (int ni = 0; ni < 4; ++ni)
                    acc[mi][ni] = MFMA16(af[mi], bfr[ni], acc[mi][ni]);
        }
        {
            bf16x8 af[4], bfr[4];
            #pragma unroll
            for (int i = 0; i < 4; ++i) {
                af[i]  = *(const bf16x8*)&As1[(wm * 64 + i * 16 + c16) * 32 + quad * 8];
                bfr[i] = *(const bf16x8*)&Bs1[(wn * 64 + i * 16 + c16) * 32 + quad * 8];
            }
            #pragma unroll
            for (int mi = 0; mi < 4; ++mi)
                #pragma unroll
                for (int ni = 0; ni < 4; ++ni)
                    acc[mi][ni] = MFMA16(af[mi], bfr[ni], acc[mi][ni]);
        }
        __syncthreads();
    }

    if (n0 < 2048) {
        #pragma unroll
        for (int mi = 0; mi < 4; ++mi) {
            #pragma unroll
            for (int ni = 0; ni < 4; ++ni) {
                const int m = m0 + wm * 64 + mi * 16 + quad * 4;  // +r
                const int n = n0 + wn * 64 + ni * 16 + c16;
                if (n < 1024) {
                    const float b0 = bq[n] + u[n & 63];
                    #pragma unroll
                    for (int r = 0; r < 4; ++r)
                        Qu[(size_t)(m + r) * 1024 + n] =
                            __float2bfloat16((acc[mi][ni][r] + b0) * C1F);
                } else {
                    const int nn = n - 1024;
                    const float b0 = bk[nn];
                    #pragma unroll
                    for (int r = 0; r < 4; ++r)
                        Kb[(size_t)(m + r) * 1024 + nn] =
                            __float2bfloat16(acc[mi][ni][r] + b0);
                }
            }
        }
    } else {
        // V epilogue: stage transposed into LDS, write coalesced.
        // Vs[nl][ml], row stride 132 elems. acc packs ml..ml+3 per u16x4.
        const int mlb = wm * 64 + quad * 4;
        #pragma unroll
        for (int ni = 0; ni < 4; ++ni) {
            const int nl = wn * 64 + ni * 16 + c16;
            const float b0 = bv[(n0 - 2048 + nl) & 1023];
            #pragma unroll
            for (int mi = 0; mi < 4; ++mi) {
                u16x4 pk;
                #pragma unroll
                for (int r = 0; r < 4; ++r)
                    pk[r] = f2bu(acc[mi][ni][r] + b0);
                *(u16x4*)&Smem[nl * 132 + mlb + mi * 16] = pk;
            }
        }
        __syncthreads();
        // Wave w writes rows nl = w*32..+31; column base = in-batch token.
        const int bb = m0 >> 10;
        const int hh0 = (n0 - 2048) >> 6;
        const int s0 = m0 & 1023;
        for (int i = 0; i < 32; ++i) {
            const int nl = w * 32 + i;
            const int R = (bb * 16 + hh0 + (nl >> 6)) * 64 + (nl & 63);
            const unsigned int val =
                *(const unsigned int*)&Smem[nl * 132 + lane * 2];
            *(unsigned int*)&Vt[(size_t)R * 1024 + s0 + lane * 2] = val;
        }
    }
}

// ---------------------------------------------------------------------------
// Final GEMM, 64x64 tiles (grid 16x64 = 1024 blocks -> 4 blocks/CU) — r8.
// ---------------------------------------------------------------------------
__global__ __launch_bounds__(256) void gemm_fin64(
    const __hip_bfloat16* __restrict__ A,
    const __hip_bfloat16* __restrict__ Bm,
    float* __restrict__ dout, const float* __restrict__ bc)
{
    __shared__ __hip_bfloat16 As[64 * 32];
    __shared__ __hip_bfloat16 Bs[64 * 32];

    const int tid  = threadIdx.x;
    const int lane = tid & 63, w = tid >> 6;
    const int quad = lane >> 4, c16 = lane & 15;
    const int wm = w >> 1, wn = w & 1;
    const int m0 = blockIdx.y * 64;
    const int n0 = blockIdx.x * 64;

    const int srow = w * 16 + (lane >> 2);
    const int scol = (lane & 3) * 8;
    const __hip_bfloat16* gA = A  + (size_t)(m0 + srow) * 1024 + scol;
    const __hip_bfloat16* gB = Bm + (size_t)(n0 + srow) * 1024 + scol;
    char* ldsA = (char*)As + (w << 10);
    char* ldsB = (char*)Bs + (w << 10);

    f32x4 acc[2][2] = {};

    for (int k0 = 0; k0 < 1024; k0 += 32) {
        gll16(gA + k0, ldsA);
        gll16(gB + k0, ldsB);
        __syncthreads();

        bf16x8 af[2], bfr[2];
        #pragma unroll
        for (int i = 0; i < 2; ++i) {
            af[i]  = *(const bf16x8*)&As[(wm * 32 + i * 16 + c16) * 32 + quad * 8];
            bfr[i] = *(const bf16x8*)&Bs[(wn * 32 + i * 16 + c16) * 32 + quad * 8];
        }
        #pragma unroll
        for (int mi = 0; mi < 2; ++mi)
            #pragma unroll
            for (int ni = 0; ni < 2; ++ni)
                acc[mi][ni] = MFMA16(af[mi], bfr[ni], acc[mi][ni]);
        __syncthreads();
    }

    #pragma unroll
    for (int mi = 0; mi < 2; ++mi) {
        #pragma unroll
        for (int ni = 0; ni < 2; ++ni) {
            const int m = m0 + wm * 32 + mi * 16 + quad * 4;
            const int n = n0 + wn * 32 + ni * 16 + c16;
            const float b0 = bc[n];
            #pragma unroll
            for (int r = 0; r < 4; ++r)
                dout[(size_t)(m + r) * 1024 + n] = acc[mi][ni][r] + b0;
        }
    }
}

// ---------------------------------------------------------------------------
// Fused relative attention — r8 version (proven ~100.5-101.3 us), unchanged.
// 64-row tiles, 512 threads (8 waves), LDS 128 KiB P -> 1 block/CU.
// Grid (bh, i0-tile): block ids of one head congruent mod 8 -> same XCD.
// Qu PRE-SCALED by C1; softmax exp2(bd'+ac'); K/Pos tile prefetch.
// ---------------------------------------------------------------------------
__device__ __forceinline__ int lidx16(int row, int c) {
    return (row << 10) + ((((c >> 3) ^ row) << 3) | (c & 7));
}

__global__ __launch_bounds__(512, 2) void attn_kernel(
    const __hip_bfloat16* __restrict__ Qu,   // [4096][1024] (q+bq+u)*C1
    const __hip_bfloat16* __restrict__ Kb,   // [4096][1024]
    const __hip_bfloat16* __restrict__ Posb, // [4096][1024] bf16 pos
    const __hip_bfloat16* __restrict__ Vt,   // [bh*64+d][s]
    const float* __restrict__ uvec, const float* __restrict__ vvec,
    __hip_bfloat16* __restrict__ O)          // [4096][1024]
{
    __shared__ __attribute__((aligned(16))) __hip_bfloat16 Ls[64 * 1024]; // 128 KiB
    __shared__ float Wsum[64 * 8];             // per-(row, wave) partial sums
    __shared__ float rs[64];                   // per-row 1/sum

    const int tid  = threadIdx.x;
    const int lane = tid & 63, w = tid >> 6;   // w in [0,8)
    const int quad = lane >> 4, c16 = lane & 15;
    const int i0 = blockIdx.y * 64;            // row tile
    const int bh = blockIdx.x;                 // head (XCD-local: id % 8 = bh % 8)
    const int b = bh >> 4, h = bh & 15;
    const size_t headoff = (size_t)h * 64;
    const size_t tokbase = (size_t)b * 1024;
    const int j2 = i0 + 64;
    const bool havej2 = (j2 < 1024);

    // Phase 1: the rel-shift leaves exactly one zero per row, at c = i+1.
    if (tid < 64) {
        const int i = i0 + tid;
        if (i + 1 < 1024) Ls[lidx16(tid, i + 1)] = __float2bfloat16(0.f);
    }

    // Per-group Qu fragment pointers (group g = rows i0+g*16 .. +15).
    const __hip_bfloat16* qup0 =
        Qu + (tokbase + i0 + c16) * 1024 + headoff + quad * 8;

    // Load Qu frags ONCE; derive Qv frags = au + (v-u)*C1 in-register.
    float dvuA[8], dvuB[8];
    #pragma unroll
    for (int j = 0; j < 8; ++j) {
        const int d = quad * 8 + j;
        dvuA[j] = (vvec[d]      - uvec[d])      * C1F;
        dvuB[j] = (vvec[d + 32] - uvec[d + 32]) * C1F;
    }
    bf16x8 au[4][2], av[4][2];
    #pragma unroll
    for (int g = 0; g < 4; ++g) {
        au[g][0] = ldg8(qup0 + (size_t)g * 16 * 1024);
        au[g][1] = ldg8(qup0 + (size_t)g * 16 * 1024 + 32);
        #pragma unroll
        for (int j = 0; j < 8; ++j) {
            av[g][0][j] = f2b(b2f(au[g][0][j]) + dvuA[j]);
            av[g][1][j] = f2b(b2f(au[g][1][j]) + dvuB[j]);
        }
    }

    // Phase 2: BD'_raw = r . (qv)^T  (swapped: lane = row j fixed, 4
    // consecutive l). Scatter: col cc = (l+j+1)&1023, row j (wrapped) or
    // j-1 (not). Extra group for raw row j2. Next Pos tile prefetched.
    {
        bf16x8 a4[2];
        if (havej2) {
            a4[0] = ldg8(qup0 + (size_t)64 * 1024);
            a4[1] = ldg8(qup0 + (size_t)64 * 1024 + 32);
            #pragma unroll
            for (int j = 0; j < 8; ++j) {
                a4[0][j] = f2b(b2f(a4[0][j]) + dvuA[j]);
                a4[1][j] = f2b(b2f(a4[1][j]) + dvuB[j]);
            }
        }
        const __hip_bfloat16* rpb =
            Posb + (tokbase + w * 128 + c16) * 1024 + headoff + quad * 8;
        bf16x8 r0 = ldg8(rpb);
        bf16x8 r1 = ldg8(rpb + 32);
        for (int t = 0; t < 8; ++t) {
            const int tn = (t + 1) & 7;              // prefetch next tile
            const bf16x8 p0 = ldg8(rpb + (size_t)tn * 16 * 1024);
            const bf16x8 p1 = ldg8(rpb + (size_t)tn * 16 * 1024 + 32);
            const int lq = w * 128 + t * 16 + quad * 4;
            #pragma unroll
            for (int g = 0; g < 4; ++g) {
                f32x4 c = (f32x4){0.f, 0.f, 0.f, 0.f};
                c = MFMA16(r0, av[g][0], c);
                c = MFMA16(r1, av[g][1], c);
                const int jl = g * 16 + c16;
                const int base2 = lq + i0 + jl + 1;   // l + j + 1 at r=0
                const int rwm1 = jl - 1;
                #pragma unroll
                for (int r = 0; r < 4; ++r) {
                    const int t1 = base2 + r;         // <= 2047
                    const int cc = t1 & 1023;
                    const int rw = rwm1 + (t1 >> 10); // +1 iff wrapped
                    if (rw >= 0)
                        Ls[lidx16(rw, cc)] = __float2bfloat16(c[r]);
                }
            }
            if (havej2) {
                f32x4 c = (f32x4){0.f, 0.f, 0.f, 0.f};
                c = MFMA16(r0, a4[0], c);
                c = MFMA16(r1, a4[1], c);
                if (c16 == 0) {
                    #pragma unroll
                    for (int r = 0; r < 4; ++r) {
                        const int cc = lq + r + i0 + 65;  // l + j2 + 1
                        if (cc < 1024)
                            Ls[lidx16(63, cc)] = __float2bfloat16(c[r]);
                    }
                }
            }
            r0 = p0; r1 = p1;
        }
    }
    __syncthreads();

    // Phase 4: AC' = k . (qu)^T; packed b64 BD read -> fused exp2 ->
    // packed b64 P write in place. Next K tile prefetched.
    {
        const __hip_bfloat16* kpb =
            Kb + (tokbase + w * 128 + c16) * 1024 + headoff + quad * 8;
        bf16x8 k0 = ldg8(kpb);
        bf16x8 k1 = ldg8(kpb + 32);
        float rsum[4] = {0.f, 0.f, 0.f, 0.f};
        for (int t = 0; t < 8; ++t) {
            const int tn = (t + 1) & 7;              // prefetch next tile
            const bf16x8 p0 = ldg8(kpb + (size_t)tn * 16 * 1024);
            const bf16x8 p1 = ldg8(kpb + (size_t)tn * 16 * 1024 + 32);
            const int cc0 = w * 128 + t * 16 + quad * 4;
            #pragma unroll
            for (int g = 0; g < 4; ++g) {
                f32x4 c = (f32x4){0.f, 0.f, 0.f, 0.f};
                c = MFMA16(k0, au[g][0], c);
                c = MFMA16(k1, au[g][1], c);
                const int jl = g * 16 + c16;
                const int idx = lidx16(jl, cc0);
                const u16x4 bd = *(const u16x4*)&Ls[idx];
                u16x4 pk;
                float s4 = 0.f;
                #pragma unroll
                for (int r = 0; r < 4; ++r) {
                    const float p =
                        __builtin_amdgcn_exp2f(bu2f(bd[r]) + c[r]);
                    s4 += p;
                    pk[r] = f2bu(p);
                }
                *(u16x4*)&Ls[idx] = pk;
                rsum[g] += s4;          // shuffles hoisted out of the loop
            }
            k0 = p0; k1 = p1;
        }
        // row jl lives in lanes {c16, c16+16, c16+32, c16+48}
        #pragma unroll
        for (int g = 0; g < 4; ++g) {
            float s = rsum[g];
            s += __shfl_xor(s, 16);
            s += __shfl_xor(s, 32);
            if (lane < 16) Wsum[(g * 16 + lane) * 8 + w] = s;
        }
    }
    __syncthreads();

    if (tid < 64) {
        float s = 0.f;
        #pragma unroll
        for (int k = 0; k < 8; ++k) s += Wsum[tid * 8 + k];
        rs[tid] = 1.f / s;
    }
    __syncthreads();

    // Phase 6: O = (P @ V) * rinv for all 4 row groups.
    // Wave w: d-tile d0=(w&3)*16, k-half kh=w>>2; V load shared by groups.
    {
        const int d0 = (w & 3) * 16;
        const int kh = w >> 2;
        const __hip_bfloat16* vp =
            Vt + ((size_t)bh * 64 + d0 + c16) * 1024 + quad * 8;
        f32x4 acc[4] = {};
        for (int kk = kh * 512; kk < kh * 512 + 512; kk += 32) {
            const bf16x8 vld = ldg8(vp + kk);
            #pragma unroll
            for (int g = 0; g < 4; ++g) {
                const bf16x8 p =
                    *(const bf16x8*)&Ls[lidx16(g * 16 + c16, kk + quad * 8)];
                acc[g] = MFMA16(p, vld, acc[g]);
            }
        }
        __syncthreads();   // all P reads done; logits LDS now reusable
        float* Lf = (float*)Ls;
        const int sbase = (w & 3) * 1024;
        if (kh == 1) {
            #pragma unroll
            for (int g = 0; g < 4; ++g)
                #pragma unroll
                for (int r = 0; r < 4; ++r)
                    Lf[sbase + g * 256 + (quad * 4 + r) * 16 + c16] = acc[g][r];
        }
        __syncthreads();
        if (kh == 0) {
            #pragma unroll
            for (int g = 0; g < 4; ++g)
                #pragma unroll
                for (int r = 0; r < 4; ++r) {
                    const int il = g * 16 + quad * 4 + r;
                    const float val =
                        (acc[g][r] + Lf[sbase + g * 256 + (quad * 4 + r) * 16 + c16])
                        * rs[il];
                    const int i = i0 + il;
                    const int d = d0 + c16;
                    O[(tokbase + i) * 1024 + headoff + d] = __float2bfloat16(val);
                }
        }
    }
}

// ---------------------------------------------------------------------------
extern "C" void kernel_launch(void* const* d_in, const int* in_sizes, int n_in,
                              void* d_out, int out_size, void* d_ws, size_t ws_size,
                              hipStream_t stream)
{
    const float* x   = (const float*)d_in[0];
    const float* u   = (const float*)d_in[1];
    const float* v   = (const float*)d_in[2];
    const float* pos = (const float*)d_in[3];
    const float* Wq  = (const float*)d_in[4];
    const float* bq  = (const float*)d_in[5];
    const float* Wk  = (const float*)d_in[6];
    const float* bk  = (const float*)d_in[7];
    const float* Wv  = (const float*)d_in[8];
    const float* bv  = (const float*)d_in[9];
    const float* Wc  = (const float*)d_in[10];
    const float* bc  = (const float*)d_in[11];

    const size_t MB = (size_t)1 << 20;
    char* ws = (char*)d_ws;
    __hip_bfloat16* Qu    = (__hip_bfloat16*)(ws + 0 * MB);
    __hip_bfloat16* Kb    = (__hip_bfloat16*)(ws + 8 * MB);
    __hip_bfloat16* Vt    = (__hip_bfloat16*)(ws + 16 * MB);
    __hip_bfloat16* xb    = (__hip_bfloat16*)(ws + 24 * MB);  // aliased w/ O
    __hip_bfloat16* O     = (__hip_bfloat16*)(ws + 24 * MB);  // x dead after QKV
    __hip_bfloat16* Posb  = (__hip_bfloat16*)(ws + 32 * MB);
    __hip_bfloat16* Wqkvb = (__hip_bfloat16*)(ws + 40 * MB);
    __hip_bfloat16* Wcb   = (__hip_bfloat16*)(ws + 46 * MB);

    cvt_kernel<<<6144, 256, 0, stream>>>(x, pos, Wq, Wk, Wv, Wc,
                                         xb, Posb, Wqkvb, Wcb);

    gemm_qkv<<<dim3(24, 32), dim3(256), 0, stream>>>(
        xb, Wqkvb, bq, bk, bv, u, Qu, Kb, Vt);

    attn_kernel<<<dim3(64, 16), dim3(512), 0, stream>>>(
        Qu, Kb, Posb, Vt, u, v, O);

    gemm_fin64<<<dim3(16, 64), dim3(256), 0, stream>>>(
        O, Wcb, (float*)d_out, bc);
}

// Round 12
// 250.977 us; speedup vs baseline: 1.0298x; 1.0298x over previous
//
#include <hip/hip_runtime.h>
#include <hip/hip_bf16.h>

// RelAttention (Transformer-XL style) on MI355X.
// fp32 in/out; internal bf16 MFMA w/ fp32 accum.
// B=4, S=1024, D=1024, H=16, DH=64, BH=64. SCALE = 1/32.
//
// Pipeline: cvt -> fused QKV GEMM (m97-style BK=32 one-plane — r8 exact;
// grid dim3(24,32), DO NOT swizzle or two-plane: r9/-r11 lessons) ->
// fused rel-attention (r8 + V prefetch in PV loop) -> final GEMM (64x64).
//
// Learned constraints: occupancy is NOT the attn lever (r1/r5/r6);
// __launch_bounds__ VGPR cap is 256/min_waves (r4); V-store coalescing
// NOT the qkv bottleneck (r8); qkv grid placement affects ATTN via
// XCD-L2 residency of its outputs (r9); fin 128x64@2/CU neutral (r10);
// qkv two-plane BK=64 regresses ~9us — qkv not barrier-drain-bound (r11).

typedef __bf16 bf16x8 __attribute__((ext_vector_type(8)));
typedef float  f32x4  __attribute__((ext_vector_type(4)));
typedef unsigned short u16x4 __attribute__((ext_vector_type(4)));

struct alignas(16) U128 { unsigned long long lo, hi; };

__device__ __forceinline__ bf16x8 ldg8(const __hip_bfloat16* p) {
    U128 u = *reinterpret_cast<const U128*>(p);
    return __builtin_bit_cast(bf16x8, u);
}

__device__ __forceinline__ __bf16 f2b(float f) {
    __hip_bfloat16 h = __float2bfloat16(f);
    return __builtin_bit_cast(__bf16, h);
}
__device__ __forceinline__ unsigned short f2bu(float f) {
    __hip_bfloat16 h = __float2bfloat16(f);
    return __builtin_bit_cast(unsigned short, h);
}
__device__ __forceinline__ float b2f(__bf16 b) {
    __hip_bfloat16 h = __builtin_bit_cast(__hip_bfloat16, b);
    return __bfloat162float(h);
}
__device__ __forceinline__ float bu2f(unsigned short u) {
    __hip_bfloat16 h = __builtin_bit_cast(__hip_bfloat16, u);
    return __bfloat162float(h);
}

__device__ __forceinline__ bf16x8 ldg8cvt(const float* p) {
    f32x4 a = *reinterpret_cast<const f32x4*>(p);
    f32x4 b = *reinterpret_cast<const f32x4*>(p + 4);
    bf16x8 r;
    r[0] = f2b(a[0]); r[1] = f2b(a[1]); r[2] = f2b(a[2]); r[3] = f2b(a[3]);
    r[4] = f2b(b[0]); r[5] = f2b(b[1]); r[6] = f2b(b[2]); r[7] = f2b(b[3]);
    return r;
}

#define MFMA16(a, b, c) __builtin_amdgcn_mfma_f32_16x16x32_bf16((a), (b), (c), 0, 0, 0)

// C1 = log2(e) * SCALE = log2(e)/32. Q is pre-scaled by this so the
// softmax exponent is exp2(bd' + ac') with NO fma and NO shift constant.
#define C1F 0.0450843334f

__device__ __forceinline__ void gll16(const __hip_bfloat16* g, void* lds_wave_base) {
    __builtin_amdgcn_global_load_lds(
        (const __attribute__((address_space(1))) void*)g,
        (__attribute__((address_space(3))) void*)lds_wave_base,
        16, 0, 0);
}

// ---------------------------------------------------------------------------
// fp32 -> bf16: x(4M), pos(4M), Wq/Wk/Wv(3M stacked), Wc(1M) = 12M elems.
// ---------------------------------------------------------------------------
__global__ __launch_bounds__(256) void cvt_kernel(
    const float* __restrict__ x,  const float* __restrict__ pos,
    const float* __restrict__ wq, const float* __restrict__ wk,
    const float* __restrict__ wv, const float* __restrict__ wc,
    __hip_bfloat16* __restrict__ xb, __hip_bfloat16* __restrict__ posb,
    __hip_bfloat16* __restrict__ wqkvb, __hip_bfloat16* __restrict__ wcb)
{
    const size_t base = ((size_t)blockIdx.x * 256 + threadIdx.x) * 8;
    const size_t M1 = (size_t)1 << 20;
    const float* src; __hip_bfloat16* dst; size_t o;
    if (base < 4*M1)        { src = x;   dst = xb;           o = base; }
    else if (base < 8*M1)   { src = pos; dst = posb;         o = base - 4*M1; }
    else if (base < 9*M1)   { src = wq;  dst = wqkvb;        o = base - 8*M1; }
    else if (base < 10*M1)  { src = wk;  dst = wqkvb + M1;   o = base - 9*M1; }
    else if (base < 11*M1)  { src = wv;  dst = wqkvb + 2*M1; o = base - 10*M1; }
    else                    { src = wc;  dst = wcb;          o = base - 11*M1; }
    *(bf16x8*)(dst + o) = ldg8cvt(src + o);
}

// ---------------------------------------------------------------------------
// QKV GEMM (m97-style, r8 exact): C[m][n] = sum_k A[m][k]*Bm[n][k].
// n<1024 -> Qu = (C+bq+u)*C1 (PRE-SCALED); <2048 -> Kb = C+bk;
// else Vt head-transposed = C+bv (LDS-staged coalesced write).
// Grid dim3(24,32) — r8 placement, do not swizzle (r9 lesson).
// ---------------------------------------------------------------------------
__global__ __launch_bounds__(256) void gemm_qkv(
    const __hip_bfloat16* __restrict__ A,
    const __hip_bfloat16* __restrict__ Bm,
    const float* __restrict__ bq, const float* __restrict__ bk,
    const float* __restrict__ bv, const float* __restrict__ u,
    __hip_bfloat16* __restrict__ Qu,
    __hip_bfloat16* __restrict__ Kb, __hip_bfloat16* __restrict__ Vt)
{
    // Union: staging (As 4096 + Bs 4096 elems) during K-loop; V-transpose
    // tile [128][132] (pad +4 breaks bank alignment) in the epilogue.
    __shared__ __attribute__((aligned(16))) __hip_bfloat16 Smem[128 * 132];
    __hip_bfloat16* As = Smem;
    __hip_bfloat16* Bs = Smem + 4096;

    const int tid  = threadIdx.x;
    const int lane = tid & 63, w = tid >> 6;
    const int quad = lane >> 4, c16 = lane & 15;
    const int wm = w >> 1, wn = w & 1;
    const int m0 = blockIdx.y * 128;
    const int n0 = blockIdx.x * 128;

    const int srow = w * 16 + (lane >> 2);
    const int scol = (lane & 3) * 8;
    const __hip_bfloat16* gA0 = A  + (size_t)(m0 + srow) * 1024 + scol;
    const __hip_bfloat16* gA1 = gA0 + (size_t)64 * 1024;
    const __hip_bfloat16* gB0 = Bm + (size_t)(n0 + srow) * 1024 + scol;
    const __hip_bfloat16* gB1 = gB0 + (size_t)64 * 1024;
    char* ldsA0 = (char*)As + (w << 10);
    char* ldsA1 = ldsA0 + 4096;
    char* ldsB0 = (char*)Bs + (w << 10);
    char* ldsB1 = ldsB0 + 4096;

    f32x4 acc[4][4] = {};

    for (int k0 = 0; k0 < 1024; k0 += 32) {
        gll16(gA0 + k0, ldsA0);
        gll16(gA1 + k0, ldsA1);
        gll16(gB0 + k0, ldsB0);
        gll16(gB1 + k0, ldsB1);
        __syncthreads();

        bf16x8 af[4], bfr[4];
        #pragma unroll
        for (int i = 0; i < 4; ++i) {
            af[i]  = *(const bf16x8*)&As[(wm * 64 + i * 16 + c16) * 32 + quad * 8];
            bfr[i] = *(const bf16x8*)&Bs[(wn * 64 + i * 16 + c16) * 32 + quad * 8];
        }
        #pragma unroll
        for (int mi = 0; mi < 4; ++mi)
            #pragma unroll
            for (int ni = 0; ni < 4; ++ni)
                acc[mi][ni] = MFMA16(af[mi], bfr[ni], acc[mi][ni]);
        __syncthreads();
    }

    if (n0 < 2048) {
        #pragma unroll
        for (int mi = 0; mi < 4; ++mi) {
            #pragma unroll
            for (int ni = 0; ni < 4; ++ni) {
                const int m = m0 + wm * 64 + mi * 16 + quad * 4;  // +r
                const int n = n0 + wn * 64 + ni * 16 + c16;
                if (n < 1024) {
                    const float b0 = bq[n] + u[n & 63];
                    #pragma unroll
                    for (int r = 0; r < 4; ++r)
                        Qu[(size_t)(m + r) * 1024 + n] =
                            __float2bfloat16((acc[mi][ni][r] + b0) * C1F);
                } else {
                    const int nn = n - 1024;
                    const float b0 = bk[nn];
                    #pragma unroll
                    for (int r = 0; r < 4; ++r)
                        Kb[(size_t)(m + r) * 1024 + nn] =
                            __float2bfloat16(acc[mi][ni][r] + b0);
                }
            }
        }
    } else {
        // V epilogue: stage transposed into LDS, write coalesced.
        // Vs[nl][ml], row stride 132 elems. acc packs ml..ml+3 per u16x4.
        const int mlb = wm * 64 + quad * 4;
        #pragma unroll
        for (int ni = 0; ni < 4; ++ni) {
            const int nl = wn * 64 + ni * 16 + c16;
            const float b0 = bv[(n0 - 2048 + nl) & 1023];
            #pragma unroll
            for (int mi = 0; mi < 4; ++mi) {
                u16x4 pk;
                #pragma unroll
                for (int r = 0; r < 4; ++r)
                    pk[r] = f2bu(acc[mi][ni][r] + b0);
                *(u16x4*)&Smem[nl * 132 + mlb + mi * 16] = pk;
            }
        }
        __syncthreads();
        // Wave w writes rows nl = w*32..+31; column base = in-batch token.
        const int bb = m0 >> 10;
        const int hh0 = (n0 - 2048) >> 6;
        const int s0 = m0 & 1023;
        for (int i = 0; i < 32; ++i) {
            const int nl = w * 32 + i;
            const int R = (bb * 16 + hh0 + (nl >> 6)) * 64 + (nl & 63);
            const unsigned int val =
                *(const unsigned int*)&Smem[nl * 132 + lane * 2];
            *(unsigned int*)&Vt[(size_t)R * 1024 + s0 + lane * 2] = val;
        }
    }
}

// ---------------------------------------------------------------------------
// Final GEMM, 64x64 tiles (grid 16x64 = 1024 blocks -> 4 blocks/CU) — r8.
// ---------------------------------------------------------------------------
__global__ __launch_bounds__(256) void gemm_fin64(
    const __hip_bfloat16* __restrict__ A,
    const __hip_bfloat16* __restrict__ Bm,
    float* __restrict__ dout, const float* __restrict__ bc)
{
    __shared__ __hip_bfloat16 As[64 * 32];
    __shared__ __hip_bfloat16 Bs[64 * 32];

    const int tid  = threadIdx.x;
    const int lane = tid & 63, w = tid >> 6;
    const int quad = lane >> 4, c16 = lane & 15;
    const int wm = w >> 1, wn = w & 1;
    const int m0 = blockIdx.y * 64;
    const int n0 = blockIdx.x * 64;

    const int srow = w * 16 + (lane >> 2);
    const int scol = (lane & 3) * 8;
    const __hip_bfloat16* gA = A  + (size_t)(m0 + srow) * 1024 + scol;
    const __hip_bfloat16* gB = Bm + (size_t)(n0 + srow) * 1024 + scol;
    char* ldsA = (char*)As + (w << 10);
    char* ldsB = (char*)Bs + (w << 10);

    f32x4 acc[2][2] = {};

    for (int k0 = 0; k0 < 1024; k0 += 32) {
        gll16(gA + k0, ldsA);
        gll16(gB + k0, ldsB);
        __syncthreads();

        bf16x8 af[2], bfr[2];
        #pragma unroll
        for (int i = 0; i < 2; ++i) {
            af[i]  = *(const bf16x8*)&As[(wm * 32 + i * 16 + c16) * 32 + quad * 8];
            bfr[i] = *(const bf16x8*)&Bs[(wn * 32 + i * 16 + c16) * 32 + quad * 8];
        }
        #pragma unroll
        for (int mi = 0; mi < 2; ++mi)
            #pragma unroll
            for (int ni = 0; ni < 2; ++ni)
                acc[mi][ni] = MFMA16(af[mi], bfr[ni], acc[mi][ni]);
        __syncthreads();
    }

    #pragma unroll
    for (int mi = 0; mi < 2; ++mi) {
        #pragma unroll
        for (int ni = 0; ni < 2; ++ni) {
            const int m = m0 + wm * 32 + mi * 16 + quad * 4;
            const int n = n0 + wn * 32 + ni * 16 + c16;
            const float b0 = bc[n];
            #pragma unroll
            for (int r = 0; r < 4; ++r)
                dout[(size_t)(m + r) * 1024 + n] = acc[mi][ni][r] + b0;
        }
    }
}

// ---------------------------------------------------------------------------
// Fused relative attention — r8 structure + V prefetch in the PV loop.
// 64-row tiles, 512 threads (8 waves), LDS 128 KiB P -> 1 block/CU.
// Grid (bh, i0-tile): block ids of one head congruent mod 8 -> same XCD.
// Qu PRE-SCALED by C1; softmax exp2(bd'+ac'); K/Pos/V tile prefetch.
// ---------------------------------------------------------------------------
__device__ __forceinline__ int lidx16(int row, int c) {
    return (row << 10) + ((((c >> 3) ^ row) << 3) | (c & 7));
}

__global__ __launch_bounds__(512, 2) void attn_kernel(
    const __hip_bfloat16* __restrict__ Qu,   // [4096][1024] (q+bq+u)*C1
    const __hip_bfloat16* __restrict__ Kb,   // [4096][1024]
    const __hip_bfloat16* __restrict__ Posb, // [4096][1024] bf16 pos
    const __hip_bfloat16* __restrict__ Vt,   // [bh*64+d][s]
    const float* __restrict__ uvec, const float* __restrict__ vvec,
    __hip_bfloat16* __restrict__ O)          // [4096][1024]
{
    __shared__ __attribute__((aligned(16))) __hip_bfloat16 Ls[64 * 1024]; // 128 KiB
    __shared__ float Wsum[64 * 8];             // per-(row, wave) partial sums
    __shared__ float rs[64];                   // per-row 1/sum

    const int tid  = threadIdx.x;
    const int lane = tid & 63, w = tid >> 6;   // w in [0,8)
    const int quad = lane >> 4, c16 = lane & 15;
    const int i0 = blockIdx.y * 64;            // row tile
    const int bh = blockIdx.x;                 // head (XCD-local: id % 8 = bh % 8)
    const int b = bh >> 4, h = bh & 15;
    const size_t headoff = (size_t)h * 64;
    const size_t tokbase = (size_t)b * 1024;
    const int j2 = i0 + 64;
    const bool havej2 = (j2 < 1024);

    // Phase 1: the rel-shift leaves exactly one zero per row, at c = i+1.
    if (tid < 64) {
        const int i = i0 + tid;
        if (i + 1 < 1024) Ls[lidx16(tid, i + 1)] = __float2bfloat16(0.f);
    }

    // Per-group Qu fragment pointers (group g = rows i0+g*16 .. +15).
    const __hip_bfloat16* qup0 =
        Qu + (tokbase + i0 + c16) * 1024 + headoff + quad * 8;

    // Load Qu frags ONCE; derive Qv frags = au + (v-u)*C1 in-register.
    float dvuA[8], dvuB[8];
    #pragma unroll
    for (int j = 0; j < 8; ++j) {
        const int d = quad * 8 + j;
        dvuA[j] = (vvec[d]      - uvec[d])      * C1F;
        dvuB[j] = (vvec[d + 32] - uvec[d + 32]) * C1F;
    }
    bf16x8 au[4][2], av[4][2];
    #pragma unroll
    for (int g = 0; g < 4; ++g) {
        au[g][0] = ldg8(qup0 + (size_t)g * 16 * 1024);
        au[g][1] = ldg8(qup0 + (size_t)g * 16 * 1024 + 32);
        #pragma unroll
        for (int j = 0; j < 8; ++j) {
            av[g][0][j] = f2b(b2f(au[g][0][j]) + dvuA[j]);
            av[g][1][j] = f2b(b2f(au[g][1][j]) + dvuB[j]);
        }
    }

    // Phase 2: BD'_raw = r . (qv)^T  (swapped: lane = row j fixed, 4
    // consecutive l). Scatter: col cc = (l+j+1)&1023, row j (wrapped) or
    // j-1 (not). Extra group for raw row j2. Next Pos tile prefetched.
    {
        bf16x8 a4[2];
        if (havej2) {
            a4[0] = ldg8(qup0 + (size_t)64 * 1024);
            a4[1] = ldg8(qup0 + (size_t)64 * 1024 + 32);
            #pragma unroll
            for (int j = 0; j < 8; ++j) {
                a4[0][j] = f2b(b2f(a4[0][j]) + dvuA[j]);
                a4[1][j] = f2b(b2f(a4[1][j]) + dvuB[j]);
            }
        }
        const __hip_bfloat16* rpb =
            Posb + (tokbase + w * 128 + c16) * 1024 + headoff + quad * 8;
        bf16x8 r0 = ldg8(rpb);
        bf16x8 r1 = ldg8(rpb + 32);
        for (int t = 0; t < 8; ++t) {
            const int tn = (t + 1) & 7;              // prefetch next tile
            const bf16x8 p0 = ldg8(rpb + (size_t)tn * 16 * 1024);
            const bf16x8 p1 = ldg8(rpb + (size_t)tn * 16 * 1024 + 32);
            const int lq = w * 128 + t * 16 + quad * 4;
            #pragma unroll
            for (int g = 0; g < 4; ++g) {
                f32x4 c = (f32x4){0.f, 0.f, 0.f, 0.f};
                c = MFMA16(r0, av[g][0], c);
                c = MFMA16(r1, av[g][1], c);
                const int jl = g * 16 + c16;
                const int base2 = lq + i0 + jl + 1;   // l + j + 1 at r=0
                const int rwm1 = jl - 1;
                #pragma unroll
                for (int r = 0; r < 4; ++r) {
                    const int t1 = base2 + r;         // <= 2047
                    const int cc = t1 & 1023;
                    const int rw = rwm1 + (t1 >> 10); // +1 iff wrapped
                    if (rw >= 0)
                        Ls[lidx16(rw, cc)] = __float2bfloat16(c[r]);
                }
            }
            if (havej2) {
                f32x4 c = (f32x4){0.f, 0.f, 0.f, 0.f};
                c = MFMA16(r0, a4[0], c);
                c = MFMA16(r1, a4[1], c);
                if (c16 == 0) {
                    #pragma unroll
                    for (int r = 0; r < 4; ++r) {
                        const int cc = lq + r + i0 + 65;  // l + j2 + 1
                        if (cc < 1024)
                            Ls[lidx16(63, cc)] = __float2bfloat16(c[r]);
                    }
                }
            }
            r0 = p0; r1 = p1;
        }
    }
    __syncthreads();

    // Phase 4: AC' = k . (qu)^T; packed b64 BD read -> fused exp2 ->
    // packed b64 P write in place. Next K tile prefetched.
    {
        const __hip_bfloat16* kpb =
            Kb + (tokbase + w * 128 + c16) * 1024 + headoff + quad * 8;
        bf16x8 k0 = ldg8(kpb);
        bf16x8 k1 = ldg8(kpb + 32);
        float rsum[4] = {0.f, 0.f, 0.f, 0.f};
        for (int t = 0; t < 8; ++t) {
            const int tn = (t + 1) & 7;              // prefetch next tile
            const bf16x8 p0 = ldg8(kpb + (size_t)tn * 16 * 1024);
            const bf16x8 p1 = ldg8(kpb + (size_t)tn * 16 * 1024 + 32);
            const int cc0 = w * 128 + t * 16 + quad * 4;
            #pragma unroll
            for (int g = 0; g < 4; ++g) {
                f32x4 c = (f32x4){0.f, 0.f, 0.f, 0.f};
                c = MFMA16(k0, au[g][0], c);
                c = MFMA16(k1, au[g][1], c);
                const int jl = g * 16 + c16;
                const int idx = lidx16(jl, cc0);
                const u16x4 bd = *(const u16x4*)&Ls[idx];
                u16x4 pk;
                float s4 = 0.f;
                #pragma unroll
                for (int r = 0; r < 4; ++r) {
                    const float p =
                        __builtin_amdgcn_exp2f(bu2f(bd[r]) + c[r]);
                    s4 += p;
                    pk[r] = f2bu(p);
                }
                *(u16x4*)&Ls[idx] = pk;
                rsum[g] += s4;          // shuffles hoisted out of the loop
            }
            k0 = p0; k1 = p1;
        }
        // row jl lives in lanes {c16, c16+16, c16+32, c16+48}
        #pragma unroll
        for (int g = 0; g < 4; ++g) {
            float s = rsum[g];
            s += __shfl_xor(s, 16);
            s += __shfl_xor(s, 32);
            if (lane < 16) Wsum[(g * 16 + lane) * 8 + w] = s;
        }
    }
    __syncthreads();

    if (tid < 64) {
        float s = 0.f;
        #pragma unroll
        for (int k = 0; k < 8; ++k) s += Wsum[tid * 8 + k];
        rs[tid] = 1.f / s;
    }
    __syncthreads();

    // Phase 6: O = (P @ V) * rinv for all 4 row groups.
    // Wave w: d-tile d0=(w&3)*16, k-half kh=w>>2; V load shared by groups,
    // prefetched one iteration ahead (same rotation as phases 2/4).
    {
        const int d0 = (w & 3) * 16;
        const int kh = w >> 2;
        const __hip_bfloat16* vpb =
            Vt + ((size_t)bh * 64 + d0 + c16) * 1024 + quad * 8 + kh * 512;
        f32x4 acc[4] = {};
        bf16x8 v0 = ldg8(vpb);
        for (int it = 0; it < 16; ++it) {
            const int itn = (it + 1) & 15;           // prefetch next V tile
            const bf16x8 pv = ldg8(vpb + itn * 32);
            const int kk = kh * 512 + it * 32;
            #pragma unroll
            for (int g = 0; g < 4; ++g) {
                const bf16x8 p =
                    *(const bf16x8*)&Ls[lidx16(g * 16 + c16, kk + quad * 8)];
                acc[g] = MFMA16(p, v0, acc[g]);
            }
            v0 = pv;
        }
        __syncthreads();   // all P reads done; logits LDS now reusable
        float* Lf = (float*)Ls;
        const int sbase = (w & 3) * 1024;
        if (kh == 1) {
            #pragma unroll
            for (int g = 0; g < 4; ++g)
                #pragma unroll
                for (int r = 0; r < 4; ++r)
                    Lf[sbase + g * 256 + (quad * 4 + r) * 16 + c16] = acc[g][r];
        }
        __syncthreads();
        if (kh == 0) {
            #pragma unroll
            for (int g = 0; g < 4; ++g)
                #pragma unroll
                for (int r = 0; r < 4; ++r) {
                    const int il = g * 16 + quad * 4 + r;
                    const float val =
                        (acc[g][r] + Lf[sbase + g * 256 + (quad * 4 + r) * 16 + c16])
                        * rs[il];
                    const int i = i0 + il;
                    const int d = d0 + c16;
                    O[(tokbase + i) * 1024 + headoff + d] = __float2bfloat16(val);
                }
        }
    }
}

// ---------------------------------------------------------------------------
extern "C" void kernel_launch(void* const* d_in, const int* in_sizes, int n_in,
                              void* d_out, int out_size, void* d_ws, size_t ws_size,
                              hipStream_t stream)
{
    const float* x   = (const float*)d_in[0];
    const float* u   = (const float*)d_in[1];
    const float* v   = (const float*)d_in[2];
    const float* pos = (const float*)d_in[3];
    const float* Wq  = (const float*)d_in[4];
    const float* bq  = (const float*)d_in[5];
    const float* Wk  = (const float*)d_in[6];
    const float* bk  = (const float*)d_in[7];
    const float* Wv  = (const float*)d_in[8];
    const float* bv  = (const float*)d_in[9];
    const float* Wc  = (const float*)d_in[10];
    const float* bc  = (const float*)d_in[11];

    const size_t MB = (size_t)1 << 20;
    char* ws = (char*)d_ws;
    __hip_bfloat16* Qu    = (__hip_bfloat16*)(ws + 0 * MB);
    __hip_bfloat16* Kb    = (__hip_bfloat16*)(ws + 8 * MB);
    __hip_bfloat16* Vt    = (__hip_bfloat16*)(ws + 16 * MB);
    __hip_bfloat16* xb    = (__hip_bfloat16*)(ws + 24 * MB);  // aliased w/ O
    __hip_bfloat16* O     = (__hip_bfloat16*)(ws + 24 * MB);  // x dead after QKV
    __hip_bfloat16* Posb  = (__hip_bfloat16*)(ws + 32 * MB);
    __hip_bfloat16* Wqkvb = (__hip_bfloat16*)(ws + 40 * MB);
    __hip_bfloat16* Wcb   = (__hip_bfloat16*)(ws + 46 * MB);

    cvt_kernel<<<6144, 256, 0, stream>>>(x, pos, Wq, Wk, Wv, Wc,
                                         xb, Posb, Wqkvb, Wcb);

    gemm_qkv<<<dim3(24, 32), dim3(256), 0, stream>>>(
        xb, Wqkvb, bq, bk, bv, u, Qu, Kb, Vt);

    attn_kernel<<<dim3(64, 16), dim3(512), 0, stream>>>(
        Qu, Kb, Posb, Vt, u, v, O);

    gemm_fin64<<<dim3(16, 64), dim3(256), 0, stream>>>(
        O, Wcb, (float*)d_out, bc);
}

// Round 13
// 233.539 us; speedup vs baseline: 1.1067x; 1.0747x over previous
//
#include <hip/hip_runtime.h>
#include <hip/hip_bf16.h>

// RelAttention (Transformer-XL style) on MI355X.
// fp32 in/out; internal bf16 MFMA w/ fp32 accum.
// B=4, S=1024, D=1024, H=16, DH=64, BH=64. SCALE = 1/32.
//
// Pipeline: cvt -> fused QKV GEMM (m97-style BK=32 — r8 exact; grid
// dim3(24,32), DO NOT swizzle: r9 lesson) -> fused rel-attention
// (FLAT-1025 layout: the rel-shift is the LINEAR map
// BD[jj][c] = Ls[(jj+1)*1024 + c - i0] over a row-stride-1025 raw
// buffer with zeros at j*1025 — phase-2 scatter becomes unconditional
// natural-layout stores, no per-element index logic) -> final GEMM 64x64.
//
// Learned constraints: occupancy is NOT the attn lever (r1/r5/r6);
// __launch_bounds__ VGPR cap is 256/min_waves (r4); V-store coalescing
// NOT the qkv bottleneck (r8); qkv grid placement affects ATTN via
// XCD-L2 residency (r9); fin 128x64@2/CU neutral (r10); qkv BK=64
// two-plane regresses (r11); load-prefetch tweaks neutral (r12) —
// attn is VALU+stall bound, so cut issued work, not load latency.

typedef __bf16 bf16x8 __attribute__((ext_vector_type(8)));
typedef float  f32x4  __attribute__((ext_vector_type(4)));
typedef unsigned short u16x4 __attribute__((ext_vector_type(4)));

struct alignas(16) U128 { unsigned long long lo, hi; };

__device__ __forceinline__ bf16x8 ldg8(const __hip_bfloat16* p) {
    U128 u = *reinterpret_cast<const U128*>(p);
    return __builtin_bit_cast(bf16x8, u);
}

__device__ __forceinline__ __bf16 f2b(float f) {
    __hip_bfloat16 h = __float2bfloat16(f);
    return __builtin_bit_cast(__bf16, h);
}
__device__ __forceinline__ unsigned short f2bu(float f) {
    __hip_bfloat16 h = __float2bfloat16(f);
    return __builtin_bit_cast(unsigned short, h);
}
__device__ __forceinline__ float b2f(__bf16 b) {
    __hip_bfloat16 h = __builtin_bit_cast(__hip_bfloat16, b);
    return __bfloat162float(h);
}
__device__ __forceinline__ float bu2f(unsigned short u) {
    __hip_bfloat16 h = __builtin_bit_cast(__hip_bfloat16, u);
    return __bfloat162float(h);
}

__device__ __forceinline__ bf16x8 ldg8cvt(const float* p) {
    f32x4 a = *reinterpret_cast<const f32x4*>(p);
    f32x4 b = *reinterpret_cast<const f32x4*>(p + 4);
    bf16x8 r;
    r[0] = f2b(a[0]); r[1] = f2b(a[1]); r[2] = f2b(a[2]); r[3] = f2b(a[3]);
    r[4] = f2b(b[0]); r[5] = f2b(b[1]); r[6] = f2b(b[2]); r[7] = f2b(b[3]);
    return r;
}

#define MFMA16(a, b, c) __builtin_amdgcn_mfma_f32_16x16x32_bf16((a), (b), (c), 0, 0, 0)

// C1 = log2(e) * SCALE = log2(e)/32. Q is pre-scaled by this so the
// softmax exponent is exp2(bd' + ac') with NO fma and NO shift constant.
#define C1F 0.0450843334f

// XOR bank-spread swizzle on flat element index (8-elem granularity:
// preserves alignment/contiguity of all u16x4/bf16x8 accesses).
__device__ __forceinline__ int fswz(int f) {
    return f ^ (((f >> 10) & 7) << 3);
}

__device__ __forceinline__ void gll16(const __hip_bfloat16* g, void* lds_wave_base) {
    __builtin_amdgcn_global_load_lds(
        (const __attribute__((address_space(1))) void*)g,
        (__attribute__((address_space(3))) void*)lds_wave_base,
        16, 0, 0);
}

// ---------------------------------------------------------------------------
// fp32 -> bf16: x(4M), pos(4M), Wq/Wk/Wv(3M stacked), Wc(1M) = 12M elems.
// ---------------------------------------------------------------------------
__global__ __launch_bounds__(256) void cvt_kernel(
    const float* __restrict__ x,  const float* __restrict__ pos,
    const float* __restrict__ wq, const float* __restrict__ wk,
    const float* __restrict__ wv, const float* __restrict__ wc,
    __hip_bfloat16* __restrict__ xb, __hip_bfloat16* __restrict__ posb,
    __hip_bfloat16* __restrict__ wqkvb, __hip_bfloat16* __restrict__ wcb)
{
    const size_t base = ((size_t)blockIdx.x * 256 + threadIdx.x) * 8;
    const size_t M1 = (size_t)1 << 20;
    const float* src; __hip_bfloat16* dst; size_t o;
    if (base < 4*M1)        { src = x;   dst = xb;           o = base; }
    else if (base < 8*M1)   { src = pos; dst = posb;         o = base - 4*M1; }
    else if (base < 9*M1)   { src = wq;  dst = wqkvb;        o = base - 8*M1; }
    else if (base < 10*M1)  { src = wk;  dst = wqkvb + M1;   o = base - 9*M1; }
    else if (base < 11*M1)  { src = wv;  dst = wqkvb + 2*M1; o = base - 10*M1; }
    else                    { src = wc;  dst = wcb;          o = base - 11*M1; }
    *(bf16x8*)(dst + o) = ldg8cvt(src + o);
}

// ---------------------------------------------------------------------------
// QKV GEMM (m97-style, r8 exact): C[m][n] = sum_k A[m][k]*Bm[n][k].
// n<1024 -> Qu = (C+bq+u)*C1 (PRE-SCALED); <2048 -> Kb = C+bk;
// else Vt head-transposed = C+bv (LDS-staged coalesced write).
// Grid dim3(24,32) — r8 placement, do not swizzle (r9 lesson).
// ---------------------------------------------------------------------------
__global__ __launch_bounds__(256) void gemm_qkv(
    const __hip_bfloat16* __restrict__ A,
    const __hip_bfloat16* __restrict__ Bm,
    const float* __restrict__ bq, const float* __restrict__ bk,
    const float* __restrict__ bv, const float* __restrict__ u,
    __hip_bfloat16* __restrict__ Qu,
    __hip_bfloat16* __restrict__ Kb, __hip_bfloat16* __restrict__ Vt)
{
    // Union: staging (As 4096 + Bs 4096 elems) during K-loop; V-transpose
    // tile [128][132] (pad +4 breaks bank alignment) in the epilogue.
    __shared__ __attribute__((aligned(16))) __hip_bfloat16 Smem[128 * 132];
    __hip_bfloat16* As = Smem;
    __hip_bfloat16* Bs = Smem + 4096;

    const int tid  = threadIdx.x;
    const int lane = tid & 63, w = tid >> 6;
    const int quad = lane >> 4, c16 = lane & 15;
    const int wm = w >> 1, wn = w & 1;
    const int m0 = blockIdx.y * 128;
    const int n0 = blockIdx.x * 128;

    const int srow = w * 16 + (lane >> 2);
    const int scol = (lane & 3) * 8;
    const __hip_bfloat16* gA0 = A  + (size_t)(m0 + srow) * 1024 + scol;
    const __hip_bfloat16* gA1 = gA0 + (size_t)64 * 1024;
    const __hip_bfloat16* gB0 = Bm + (size_t)(n0 + srow) * 1024 + scol;
    const __hip_bfloat16* gB1 = gB0 + (size_t)64 * 1024;
    char* ldsA0 = (char*)As + (w << 10);
    char* ldsA1 = ldsA0 + 4096;
    char* ldsB0 = (char*)Bs + (w << 10);
    char* ldsB1 = ldsB0 + 4096;

    f32x4 acc[4][4] = {};

    for (int k0 = 0; k0 < 1024; k0 += 32) {
        gll16(gA0 + k0, ldsA0);
        gll16(gA1 + k0, ldsA1);
        gll16(gB0 + k0, ldsB0);
        gll16(gB1 + k0, ldsB1);
        __syncthreads();

        bf16x8 af[4], bfr[4];
        #pragma unroll
        for (int i = 0; i < 4; ++i) {
            af[i]  = *(const bf16x8*)&As[(wm * 64 + i * 16 + c16) * 32 + quad * 8];
            bfr[i] = *(const bf16x8*)&Bs[(wn * 64 + i * 16 + c16) * 32 + quad * 8];
        }
        #pragma unroll
        for (int mi = 0; mi < 4; ++mi)
            #pragma unroll
            for (int ni = 0; ni < 4; ++ni)
                acc[mi][ni] = MFMA16(af[mi], bfr[ni], acc[mi][ni]);
        __syncthreads();
    }

    if (n0 < 2048) {
        #pragma unroll
        for (int mi = 0; mi < 4; ++mi) {
            #pragma unroll
            for (int ni = 0; ni < 4; ++ni) {
                const int m = m0 + wm * 64 + mi * 16 + quad * 4;  // +r
                const int n = n0 + wn * 64 + ni * 16 + c16;
                if (n < 1024) {
                    const float b0 = bq[n] + u[n & 63];
                    #pragma unroll
                    for (int r = 0; r < 4; ++r)
                        Qu[(size_t)(m + r) * 1024 + n] =
                            __float2bfloat16((acc[mi][ni][r] + b0) * C1F);
                } else {
                    const int nn = n - 1024;
                    const float b0 = bk[nn];
                    #pragma unroll
                    for (int r = 0; r < 4; ++r)
                        Kb[(size_t)(m + r) * 1024 + nn] =
                            __float2bfloat16(acc[mi][ni][r] + b0);
                }
            }
        }
    } else {
        // V epilogue: stage transposed into LDS, write coalesced.
        // Vs[nl][ml], row stride 132 elems. acc packs ml..ml+3 per u16x4.
        const int mlb = wm * 64 + quad * 4;
        #pragma unroll
        for (int ni = 0; ni < 4; ++ni) {
            const int nl = wn * 64 + ni * 16 + c16;
            const float b0 = bv[(n0 - 2048 + nl) & 1023];
            #pragma unroll
            for (int mi = 0; mi < 4; ++mi) {
                u16x4 pk;
                #pragma unroll
                for (int r = 0; r < 4; ++r)
                    pk[r] = f2bu(acc[mi][ni][r] + b0);
                *(u16x4*)&Smem[nl * 132 + mlb + mi * 16] = pk;
            }
        }
        __syncthreads();
        // Wave w writes rows nl = w*32..+31; column base = in-batch token.
        const int bb = m0 >> 10;
        const int hh0 = (n0 - 2048) >> 6;
        const int s0 = m0 & 1023;
        for (int i = 0; i < 32; ++i) {
            const int nl = w * 32 + i;
            const int R = (bb * 16 + hh0 + (nl >> 6)) * 64 + (nl & 63);
            const unsigned int val =
                *(const unsigned int*)&Smem[nl * 132 + lane * 2];
            *(unsigned int*)&Vt[(size_t)R * 1024 + s0 + lane * 2] = val;
        }
    }
}

// ---------------------------------------------------------------------------
// Final GEMM, 64x64 tiles (grid 16x64 = 1024 blocks -> 4 blocks/CU) — r8.
// ---------------------------------------------------------------------------
__global__ __launch_bounds__(256) void gemm_fin64(
    const __hip_bfloat16* __restrict__ A,
    const __hip_bfloat16* __restrict__ Bm,
    float* __restrict__ dout, const float* __restrict__ bc)
{
    __shared__ __hip_bfloat16 As[64 * 32];
    __shared__ __hip_bfloat16 Bs[64 * 32];

    const int tid  = threadIdx.x;
    const int lane = tid & 63, w = tid >> 6;
    const int quad = lane >> 4, c16 = lane & 15;
    const int wm = w >> 1, wn = w & 1;
    const int m0 = blockIdx.y * 64;
    const int n0 = blockIdx.x * 64;

    const int srow = w * 16 + (lane >> 2);
    const int scol = (lane & 3) * 8;
    const __hip_bfloat16* gA = A  + (size_t)(m0 + srow) * 1024 + scol;
    const __hip_bfloat16* gB = Bm + (size_t)(n0 + srow) * 1024 + scol;
    char* ldsA = (char*)As + (w << 10);
    char* ldsB = (char*)Bs + (w << 10);

    f32x4 acc[2][2] = {};

    for (int k0 = 0; k0 < 1024; k0 += 32) {
        gll16(gA + k0, ldsA);
        gll16(gB + k0, ldsB);
        __syncthreads();

        bf16x8 af[2], bfr[2];
        #pragma unroll
        for (int i = 0; i < 2; ++i) {
            af[i]  = *(const bf16x8*)&As[(wm * 32 + i * 16 + c16) * 32 + quad * 8];
            bfr[i] = *(const bf16x8*)&Bs[(wn * 32 + i * 16 + c16) * 32 + quad * 8];
        }
        #pragma unroll
        for (int mi = 0; mi < 2; ++mi)
            #pragma unroll
            for (int ni = 0; ni < 2; ++ni)
                acc[mi][ni] = MFMA16(af[mi], bfr[ni], acc[mi][ni]);
        __syncthreads();
    }

    #pragma unroll
    for (int mi = 0; mi < 2; ++mi) {
        #pragma unroll
        for (int ni = 0; ni < 2; ++ni) {
            const int m = m0 + wm * 32 + mi * 16 + quad * 4;
            const int n = n0 + wn * 32 + ni * 16 + c16;
            const float b0 = bc[n];
            #pragma unroll
            for (int r = 0; r < 4; ++r)
                dout[(size_t)(m + r) * 1024 + n] = acc[mi][ni][r] + b0;
        }
    }
}

// ---------------------------------------------------------------------------
// Fused relative attention — FLAT-1025 rel-shift layout.
// 64-row tiles, 512 threads (8 waves), 1 block/CU.
//
// Derivation (from the reference's pad+reshape): with raw BD rows stored
// at flat slots j*1025 + 1 + l (local raw row j = global i0+j) and ZERO
// at j*1025, the shifted matrix is the LINEAR gather
//     BD[jj][c] = Ls[(jj+1)*1024 + c - i0]
// (fl % 1025 == 0 lands exactly on the injected-zero slots; row j2 =
// local raw row 64). Verified at wrap/zero/boundary corners for i0=0
// and i0=960. Phase 2 therefore stores raw rows at natural addresses
// with NO conditionals; phase 4 reads aligned u16x4 (i0 % 4 == 0) and
// writes P in place; phase 6 reads P through the same map. All accesses
// go through fswz() (XOR bank spread, 8-elem granularity).
// Qu PRE-SCALED by C1; softmax exp2(bd'+ac'); K/Pos/V tile prefetch.
// ---------------------------------------------------------------------------
__global__ __launch_bounds__(512, 2) void attn_kernel(
    const __hip_bfloat16* __restrict__ Qu,   // [4096][1024] (q+bq+u)*C1
    const __hip_bfloat16* __restrict__ Kb,   // [4096][1024]
    const __hip_bfloat16* __restrict__ Posb, // [4096][1024] bf16 pos
    const __hip_bfloat16* __restrict__ Vt,   // [bh*64+d][s]
    const float* __restrict__ uvec, const float* __restrict__ vvec,
    __hip_bfloat16* __restrict__ O)          // [4096][1024]
{
    // 65 raw rows * 1025 + 1 = 66626 slots; +XOR headroom (<= +56) -> 66688.
    __shared__ __attribute__((aligned(16))) __hip_bfloat16 Ls[66688]; // ~130 KiB
    __shared__ float Wsum[64 * 8];             // per-(row, wave) partial sums
    __shared__ float rs[64];                   // per-row 1/sum

    const int tid  = threadIdx.x;
    const int lane = tid & 63, w = tid >> 6;   // w in [0,8)
    const int quad = lane >> 4, c16 = lane & 15;
    const int i0 = blockIdx.y * 64;            // row tile
    const int bh = blockIdx.x;                 // head (XCD-local: id % 8 = bh % 8)
    const int b = bh >> 4, h = bh & 15;
    const size_t headoff = (size_t)h * 64;
    const size_t tokbase = (size_t)b * 1024;
    const int j2 = i0 + 64;
    const bool havej2 = (j2 < 1024);

    // Phase 1: zero slots of the flat-1025 layout (j = 1..64).
    if (tid >= 1 && tid <= 64) {
        const int f = tid * 1025;
        Ls[fswz(f)] = __float2bfloat16(0.f);
    }

    // Per-group Qu fragment pointers (group g = rows i0+g*16 .. +15).
    const __hip_bfloat16* qup0 =
        Qu + (tokbase + i0 + c16) * 1024 + headoff + quad * 8;

    // Load Qu frags ONCE; derive Qv frags = au + (v-u)*C1 in-register.
    float dvuA[8], dvuB[8];
    #pragma unroll
    for (int j = 0; j < 8; ++j) {
        const int d = quad * 8 + j;
        dvuA[j] = (vvec[d]      - uvec[d])      * C1F;
        dvuB[j] = (vvec[d + 32] - uvec[d + 32]) * C1F;
    }
    bf16x8 au[4][2], av[4][2];
    #pragma unroll
    for (int g = 0; g < 4; ++g) {
        au[g][0] = ldg8(qup0 + (size_t)g * 16 * 1024);
        au[g][1] = ldg8(qup0 + (size_t)g * 16 * 1024 + 32);
        #pragma unroll
        for (int j = 0; j < 8; ++j) {
            av[g][0][j] = f2b(b2f(au[g][0][j]) + dvuA[j]);
            av[g][1][j] = f2b(b2f(au[g][1][j]) + dvuB[j]);
        }
    }

    // Phase 2: BD'_raw = r . (qv)^T (swapped: lane = raw row jl fixed,
    // 4 consecutive l). Store at NATURAL flat-1025 addresses — no
    // conditionals, no shift logic. Extra group = raw row 64 (j2).
    {
        bf16x8 a4[2];
        if (havej2) {
            a4[0] = ldg8(qup0 + (size_t)64 * 1024);
            a4[1] = ldg8(qup0 + (size_t)64 * 1024 + 32);
            #pragma unroll
            for (int j = 0; j < 8; ++j) {
                a4[0][j] = f2b(b2f(a4[0][j]) + dvuA[j]);
                a4[1][j] = f2b(b2f(a4[1][j]) + dvuB[j]);
            }
        }
        const __hip_bfloat16* rpb =
            Posb + (tokbase + w * 128 + c16) * 1024 + headoff + quad * 8;
        bf16x8 r0 = ldg8(rpb);
        bf16x8 r1 = ldg8(rpb + 32);
        for (int t = 0; t < 8; ++t) {
            const int tn = (t + 1) & 7;              // prefetch next tile
            const bf16x8 p0 = ldg8(rpb + (size_t)tn * 16 * 1024);
            const bf16x8 p1 = ldg8(rpb + (size_t)tn * 16 * 1024 + 32);
            const int lq = w * 128 + t * 16 + quad * 4;
            #pragma unroll
            for (int g = 0; g < 4; ++g) {
                f32x4 c = (f32x4){0.f, 0.f, 0.f, 0.f};
                c = MFMA16(r0, av[g][0], c);
                c = MFMA16(r1, av[g][1], c);
                const int jl = g * 16 + c16;
                const int fb = (jl << 10) + jl + 1 + lq;   // jl*1025 + 1 + lq
                #pragma unroll
                for (int r = 0; r < 4; ++r)
                    Ls[fswz(fb + r)] = __float2bfloat16(c[r]);
            }
            if (havej2) {
                f32x4 c = (f32x4){0.f, 0.f, 0.f, 0.f};
                c = MFMA16(r0, a4[0], c);
                c = MFMA16(r1, a4[1], c);
                if (c16 == 0) {
                    const int fb4 = 65601 + lq;            // 64*1025 + 1 + lq
                    #pragma unroll
                    for (int r = 0; r < 4; ++r)
                        Ls[fswz(fb4 + r)] = __float2bfloat16(c[r]);
                }
            }
            r0 = p0; r1 = p1;
        }
    }
    __syncthreads();

    // Phase 4: AC' = k . (qu)^T; aligned u16x4 BD read via the linear
    // shift map -> fused exp2 -> u16x4 P write in place.
    {
        const __hip_bfloat16* kpb =
            Kb + (tokbase + w * 128 + c16) * 1024 + headoff + quad * 8;
        bf16x8 k0 = ldg8(kpb);
        bf16x8 k1 = ldg8(kpb + 32);
        float rsum[4] = {0.f, 0.f, 0.f, 0.f};
        for (int t = 0; t < 8; ++t) {
            const int tn = (t + 1) & 7;              // prefetch next tile
            const bf16x8 p0 = ldg8(kpb + (size_t)tn * 16 * 1024);
            const bf16x8 p1 = ldg8(kpb + (size_t)tn * 16 * 1024 + 32);
            const int cc0 = w * 128 + t * 16 + quad * 4;
            #pragma unroll
            for (int g = 0; g < 4; ++g) {
                f32x4 c = (f32x4){0.f, 0.f, 0.f, 0.f};
                c = MFMA16(k0, au[g][0], c);
                c = MFMA16(k1, au[g][1], c);
                const int jl = g * 16 + c16;
                const int fl0 = ((jl + 1) << 10) + cc0 - i0;
                const int fs = fswz(fl0);
                const u16x4 bd = *(const u16x4*)&Ls[fs];
                u16x4 pk;
                float s4 = 0.f;
                #pragma unroll
                for (int r = 0; r < 4; ++r) {
                    const float p =
                        __builtin_amdgcn_exp2f(bu2f(bd[r]) + c[r]);
                    s4 += p;
                    pk[r] = f2bu(p);
                }
                *(u16x4*)&Ls[fs] = pk;
                rsum[g] += s4;          // shuffles hoisted out of the loop
            }
            k0 = p0; k1 = p1;
        }
        // row jl lives in lanes {c16, c16+16, c16+32, c16+48}
        #pragma unroll
        for (int g = 0; g < 4; ++g) {
            float s = rsum[g];
            s += __shfl_xor(s, 16);
            s += __shfl_xor(s, 32);
            if (lane < 16) Wsum[(g * 16 + lane) * 8 + w] = s;
        }
    }
    __syncthreads();

    if (tid < 64) {
        float s = 0.f;
        #pragma unroll
        for (int k = 0; k < 8; ++k) s += Wsum[tid * 8 + k];
        rs[tid] = 1.f / s;
    }
    __syncthreads();

    // Phase 6: O = (P @ V) * rinv for all 4 row groups.
    // Wave w: d-tile d0=(w&3)*16, k-half kh=w>>2; V load shared by groups,
    // prefetched one iteration ahead. P read through the linear map.
    {
        const int d0 = (w & 3) * 16;
        const int kh = w >> 2;
        const __hip_bfloat16* vpb =
            Vt + ((size_t)bh * 64 + d0 + c16) * 1024 + quad * 8 + kh * 512;
        f32x4 acc[4] = {};
        bf16x8 v0 = ldg8(vpb);
        for (int it = 0; it < 16; ++it) {
            const int itn = (it + 1) & 15;           // prefetch next V tile
            const bf16x8 pv = ldg8(vpb + itn * 32);
            const int kk = kh * 512 + it * 32;
            #pragma unroll
            for (int g = 0; g < 4; ++g) {
                const int fl = ((g * 16 + c16 + 1) << 10) + kk + quad * 8 - i0;
                const bf16x8 p = *(const bf16x8*)&Ls[fswz(fl)];
                acc[g] = MFMA16(p, v0, acc[g]);
            }
            v0 = pv;
        }
        __syncthreads();   // all P reads done; logits LDS now reusable
        float* Lf = (float*)Ls;
        const int sbase = (w & 3) * 1024;
        if (kh == 1) {
            #pragma unroll
            for (int g = 0; g < 4; ++g)
                #pragma unroll
                for (int r = 0; r < 4; ++r)
                    Lf[sbase + g * 256 + (quad * 4 + r) * 16 + c16] = acc[g][r];
        }
        __syncthreads();
        if (kh == 0) {
            #pragma unroll
            for (int g = 0; g < 4; ++g)
                #pragma unroll
                for (int r = 0; r < 4; ++r) {
                    const int il = g * 16 + quad * 4 + r;
                    const float val =
                        (acc[g][r] + Lf[sbase + g * 256 + (quad * 4 + r) * 16 + c16])
                        * rs[il];
                    const int i = i0 + il;
                    const int d = d0 + c16;
                    O[(tokbase + i) * 1024 + headoff + d] = __float2bfloat16(val);
                }
        }
    }
}

// ---------------------------------------------------------------------------
extern "C" void kernel_launch(void* const* d_in, const int* in_sizes, int n_in,
                              void* d_out, int out_size, void* d_ws, size_t ws_size,
                              hipStream_t stream)
{
    const float* x   = (const float*)d_in[0];
    const float* u   = (const float*)d_in[1];
    const float* v   = (const float*)d_in[2];
    const float* pos = (const float*)d_in[3];
    const float* Wq  = (const float*)d_in[4];
    const float* bq  = (const float*)d_in[5];
    const float* Wk  = (const float*)d_in[6];
    const float* bk  = (const float*)d_in[7];
    const float* Wv  = (const float*)d_in[8];
    const float* bv  = (const float*)d_in[9];
    const float* Wc  = (const float*)d_in[10];
    const float* bc  = (const float*)d_in[11];

    const size_t MB = (size_t)1 << 20;
    char* ws = (char*)d_ws;
    __hip_bfloat16* Qu    = (__hip_bfloat16*)(ws + 0 * MB);
    __hip_bfloat16* Kb    = (__hip_bfloat16*)(ws + 8 * MB);
    __hip_bfloat16* Vt    = (__hip_bfloat16*)(ws + 16 * MB);
    __hip_bfloat16* xb    = (__hip_bfloat16*)(ws + 24 * MB);  // aliased w/ O
    __hip_bfloat16* O     = (__hip_bfloat16*)(ws + 24 * MB);  // x dead after QKV
    __hip_bfloat16* Posb  = (__hip_bfloat16*)(ws + 32 * MB);
    __hip_bfloat16* Wqkvb = (__hip_bfloat16*)(ws + 40 * MB);
    __hip_bfloat16* Wcb   = (__hip_bfloat16*)(ws + 46 * MB);

    cvt_kernel<<<6144, 256, 0, stream>>>(x, pos, Wq, Wk, Wv, Wc,
                                         xb, Posb, Wqkvb, Wcb);

    gemm_qkv<<<dim3(24, 32), dim3(256), 0, stream>>>(
        xb, Wqkvb, bq, bk, bv, u, Qu, Kb, Vt);

    attn_kernel<<<dim3(64, 16), dim3(512), 0, stream>>>(
        Qu, Kb, Posb, Vt, u, v, O);

    gemm_fin64<<<dim3(16, 64), dim3(256), 0, stream>>>(
        O, Wcb, (float*)d_out, bc);
}